// Round 1
// baseline (385.068 us; speedup 1.0000x reference)
//
#include <hip/hip_runtime.h>
#include <hip/hip_cooperative_groups.h>

namespace cg = cooperative_groups;

#define NN 2048   // nodes
#define NW 64     // u32 words per bitmap row (2048 bits)
#define NBLK 512  // 4 nodes per block

// Single cooperative kernel: build -> pandeg+lin1 -> spmm16 -> final1+lin2
// -> spmm32 -> final2, with grid-wide syncs between cross-block phases.
// Block b owns nodes 4b..4b+3 (wave w handles node 4b+w) for ALL phases, so
// dinv, own-row y/t values and the in-neighbor list live in LDS throughout.
__global__ void __launch_bounds__(256, 2) k_mega(
        const float* __restrict__ x, const int* __restrict__ ei,
        const float* __restrict__ fw1, const float* __restrict__ W1,
        const float* __restrict__ b1,
        const float* __restrict__ fw2, const float* __restrict__ W2,
        const float* __restrict__ b2,
        float* __restrict__ out,
        unsigned* __restrict__ Abits,
        float* __restrict__ y1, float* __restrict__ t1,
        float* __restrict__ y2, float* __restrict__ t2,
        int E)
{
    cg::grid_group grid = cg::this_grid();

    __shared__ unsigned Arow[4][NW];    // out-edge bitmaps of our 4 nodes
    __shared__ unsigned ATrow[4][NW];   // in-edge bitmaps of our 4 nodes
    __shared__ int cnt[4][NN];          // path-2 counts (one array per wave)
    __shared__ int nout[4][128];        // out-neighbor list (pandeg scatter)
    __shared__ int nin[4][64];          // in-neighbor list (phases 3-6)
    __shared__ int noutc[4], ninc[4];
    __shared__ float xs[528];           // lin1 x-row stage, group-padded
    __shared__ float sdinv1[4], sdinv2[4];
    __shared__ float sy1[4][16], st1[4][16];
    __shared__ float sy2[4][32], st2[4][32];

    const int tid = threadIdx.x, blk = blockIdx.x;
    const int w = tid >> 6, lane = tid & 63;
    const int i = blk * 4 + w;          // this wave's node

    if (tid < 4) { noutc[tid] = 0; ninc[tid] = 0; }
    (&Arow[0][0])[tid]  = 0u;           // 256 threads cover 4*64 words
    (&ATrow[0][0])[tid] = 0u;
    __syncthreads();

    // ---- phase A: block-local adjacency build (dedup via bitmap OR) ------
    // Each block scans the whole edge list (L2-resident, 256 KB) and keeps
    // only edges touching its 4 rows. No global zero, no global atomics.
    {
        const int4* s4p = (const int4*)ei;
        const int4* d4p = (const int4*)(ei + E);
        const int base = blk << 2;
#define EDGE_ROW(SS, DD) { \
        int sv_ = (SS) & (NN - 1), dv_ = (DD) & (NN - 1); \
        int r_ = sv_ - base; \
        if ((unsigned)r_ < 4u) atomicOr(&Arow[r_][dv_ >> 5], 1u << (dv_ & 31)); \
        r_ = dv_ - base; \
        if ((unsigned)r_ < 4u) atomicOr(&ATrow[r_][sv_ >> 5], 1u << (sv_ & 31)); }
        for (int e4 = tid; e4 < (E >> 2); e4 += 256) {
            int4 s4 = s4p[e4], d4 = d4p[e4];
            EDGE_ROW(s4.x, d4.x)
            EDGE_ROW(s4.y, d4.y)
            EDGE_ROW(s4.z, d4.z)
            EDGE_ROW(s4.w, d4.w)
        }
        for (int e = (E & ~3) + tid; e < E; e += 256)   // tail (E%4), usually empty
            EDGE_ROW(ei[e], ei[E + e])
#undef EDGE_ROW
    }
    __syncthreads();
    Abits[i * NW + lane] = Arow[w][lane];   // publish A rows for scatter phase
    grid.sync();

    // ---- phase B: pandeg (one wave per node) ------------------------------
    {
        int4 z4 = make_int4(0, 0, 0, 0);
        int4* c4 = (int4*)cnt[w];
        for (int t = lane; t < (NN >> 2); t += 64) c4[t] = z4;
    }
    {
        unsigned bits = Arow[w][lane];      // enumerate out-neighbors
        while (bits) {
            int b = __ffs(bits) - 1; bits &= bits - 1;
            int slot = atomicAdd(&noutc[w], 1);
            if (slot < 128) nout[w][slot] = lane * 32 + b;
        }
    }
    __syncthreads();
    const float w10 = fw1[0], w11 = fw1[1], w12 = fw1[2];
    const float w20 = fw2[0], w21 = fw2[1], w22 = fw2[2];
    {
        int nco = noutc[w] < 128 ? noutc[w] : 128;
        unsigned nxt = 0u;                   // prefetch next neighbor row
        if (nco) nxt = Abits[nout[w][0] * NW + lane];
        for (int n = 0; n < nco; ++n) {
            unsigned bits = nxt;
            if (n + 1 < nco) nxt = Abits[nout[w][n + 1] * NW + lane];
            while (bits) {
                int b = __ffs(bits) - 1; bits &= bits - 1;
                atomicAdd(&cnt[w][lane * 32 + b], 1);
            }
        }
    }
    // cnt[w] only touched by wave w -> DS ops are wave-ordered, no barrier
    int c1 = 0, c2 = 0;
    for (int it = 0; it < 32; ++it) {        // stride-64 scan: conflict-free
        int j = it * 64 + lane;
        float a = ((Arow[w][j >> 5] >> (j & 31)) & 1u) ? 1.f : 0.f;
        float cp = (float)cnt[w][j];
        float dg = (j == i) ? 1.f : 0.f;
        c1 += ((w10 * dg + w11 * a + w12 * cp) != 0.f) ? 1 : 0;
        c2 += ((w20 * dg + w21 * a + w22 * cp) != 0.f) ? 1 : 0;
    }
    for (int o = 32; o; o >>= 1) { c1 += __shfl_xor(c1, o); c2 += __shfl_xor(c2, o); }
    if (lane == 0) {
        sdinv1[w] = c1 > 0 ? rsqrtf((float)c1) : 0.f;
        sdinv2[w] = c2 > 0 ? rsqrtf((float)c2) : 0.f;
    }
    {
        unsigned bits = ATrow[w][lane];      // in-neighbor list, kept for 3-6
        while (bits) {
            int b = __ffs(bits) - 1; bits &= bits - 1;
            int slot = atomicAdd(&ninc[w], 1);
            if (slot < 64) nin[w][slot] = lane * 32 + b;
        }
    }
    __syncthreads();

    // ---- phase C: lin1, y1[i][c] = dinv1[i]*(x[i,:].W1[c,:]+b1[c]) --------
    {
        int cch = tid >> 4, seg = tid & 15;
        for (int s = 0; s < 4; ++s) {
            if (tid < 128) {                 // coalesced float4 stage
                float4 v = ((const float4*)(x + (blk * 4 + s) * 512))[tid];
                int f = tid * 4, m = f + (f >> 5);   // group-pad: conflict-free
                xs[m] = v.x; xs[m + 1] = v.y; xs[m + 2] = v.z; xs[m + 3] = v.w;
            }
            __syncthreads();
            const float* wr = W1 + cch * 512 + seg * 32;
            const float* xr = xs + seg * 33;
            float sacc = 0.f;
#pragma unroll
            for (int f = 0; f < 32; ++f) sacc += xr[f] * wr[f];
            for (int o = 8; o; o >>= 1) sacc += __shfl_down(sacc, o, 16);
            if (seg == 0) {
                float v = sdinv1[s] * (sacc + b1[cch]);
                y1[(blk * 4 + s) * 16 + cch] = v;
                sy1[s][cch] = v;
            }
            __syncthreads();
        }
    }
    grid.sync();

    // ---- phase D: spmm16  t1 = P y1 ---------------------------------------
    const int ncin = ninc[w] < 64 ? ninc[w] : 64;
    {
        int c = lane & 15, grp = lane >> 4;
        float acc = 0.f;
#pragma unroll 2
        for (int n = grp; n < ncin; n += 4) acc += y1[nin[w][n] * 16 + c];
        acc += __shfl_down(acc, 32);
        acc += __shfl_down(acc, 16);
        if (lane < 16) { t1[i * 16 + c] = acc; st1[w][c] = acc; }
    }
    grid.sync();

    // ---- phase E: layer-1 tail + fused layer-2 linear ---------------------
    {
        int c = lane & 15, grp = lane >> 4;
        float acc = 0.f;
#pragma unroll 2
        for (int n = grp; n < ncin; n += 4) acc += t1[nin[w][n] * 16 + c];
        acc += __shfl_down(acc, 32);
        acc += __shfl_down(acc, 16);
        float z = sdinv1[w] * (w10 * sy1[w][c] + w11 * st1[w][c] + w12 * acc);
        z = z > 0.f ? z : 0.f;               // relu; valid on lanes 0..15
        float s2 = 0.f;
        const float* w2r = W2 + (lane & 31) * 16;
#pragma unroll
        for (int f = 0; f < 16; ++f) s2 += __shfl(z, f) * w2r[f];
        if (lane < 32) {
            float v = sdinv2[w] * (s2 + b2[lane]);
            y2[i * 32 + lane] = v; sy2[w][lane] = v;
        }
    }
    grid.sync();

    // ---- phase F: spmm32  t2 = P y2 ---------------------------------------
    {
        int c = lane & 31, grp = lane >> 5;
        float acc = 0.f;
#pragma unroll 2
        for (int n = grp; n < ncin; n += 2) acc += y2[nin[w][n] * 32 + c];
        acc += __shfl_down(acc, 32);
        if (lane < 32) { t2[i * 32 + c] = acc; st2[w][c] = acc; }
    }
    grid.sync();

    // ---- phase G: layer-2 tail + log_softmax ------------------------------
    {
        int c = lane & 31, grp = lane >> 5;
        float acc = 0.f;
#pragma unroll 2
        for (int n = grp; n < ncin; n += 2) acc += t2[nin[w][n] * 32 + c];
        acc += __shfl_down(acc, 32);         // lanes 0..31 hold full sum
        float o = sdinv2[w] * (w20 * sy2[w][c] + w21 * st2[w][c] + w22 * acc);
        float m = o;
        for (int k = 16; k; k >>= 1) m = fmaxf(m, __shfl_xor(m, k, 32));
        float e = expf(o - m);
        float ssum = e;
        for (int k = 16; k; k >>= 1) ssum += __shfl_xor(ssum, k, 32);
        if (lane < 32) out[i * 32 + c] = o - m - logf(ssum);
    }
}

extern "C" void kernel_launch(void* const* d_in, const int* in_sizes, int n_in,
                              void* d_out, int out_size, void* d_ws, size_t ws_size,
                              hipStream_t stream) {
    const float* x   = (const float*)d_in[0];
    const int*   ei  = (const int*)d_in[1];
    const float* fw1 = (const float*)d_in[2];
    const float* W1  = (const float*)d_in[3];
    const float* b1  = (const float*)d_in[4];
    const float* fw2 = (const float*)d_in[5];
    const float* W2  = (const float*)d_in[6];
    const float* b2  = (const float*)d_in[7];
    float* out = (float*)d_out;
    int E = in_sizes[1] / 2;

    char* ws = (char*)d_ws;
    size_t off = 0;
    auto alloc = [&](size_t bytes) { void* p = ws + off; off += (bytes + 255) & ~size_t(255); return p; };
    unsigned* Abits = (unsigned*)alloc(NN * NW * 4);
    float* y1 = (float*)alloc(NN * 16 * 4);
    float* t1 = (float*)alloc(NN * 16 * 4);
    float* y2 = (float*)alloc(NN * 32 * 4);
    float* t2 = (float*)alloc(NN * 32 * 4);
    (void)ws_size; (void)n_in; (void)out_size;

    void* args[] = { (void*)&x, (void*)&ei, (void*)&fw1, (void*)&W1, (void*)&b1,
                     (void*)&fw2, (void*)&W2, (void*)&b2, (void*)&out,
                     (void*)&Abits, (void*)&y1, (void*)&t1, (void*)&y2, (void*)&t2,
                     (void*)&E };
    hipLaunchCooperativeKernel((void*)k_mega, dim3(NBLK), dim3(256), args, 0, stream);
}

// Round 2
// 134.750 us; speedup vs baseline: 2.8576x; 2.8576x over previous
//
#include <hip/hip_runtime.h>

#define NN 2048   // nodes
#define NW 64     // u32 words per bitmap row (2048 bits)
#define BBLK 512  // build blocks: 4 nodes per block

// ---- K1: block-local adjacency build (no zero pass, no global atomics) -----
// Each block scans the whole edge list (256 KB, L2-resident) and keeps only
// edges touching its 4 rows; writes deduped A and A^T row bitmaps.
__global__ void __launch_bounds__(256) k_build(const int* __restrict__ ei, int E,
        unsigned* __restrict__ Abits, unsigned* __restrict__ ATbits) {
    __shared__ unsigned Arow[4][NW], ATrow[4][NW];
    int tid = threadIdx.x, blk = blockIdx.x;
    (&Arow[0][0])[tid]  = 0u;            // 256 threads cover 4*64 words
    (&ATrow[0][0])[tid] = 0u;
    __syncthreads();
    const int4* s4p = (const int4*)ei;
    const int4* d4p = (const int4*)(ei + E);
    const int base = blk << 2;
#define EDGE_ROW(SS, DD) { \
        int sv_ = (SS) & (NN - 1), dv_ = (DD) & (NN - 1); \
        int r_ = sv_ - base; \
        if ((unsigned)r_ < 4u) atomicOr(&Arow[r_][dv_ >> 5], 1u << (dv_ & 31)); \
        r_ = dv_ - base; \
        if ((unsigned)r_ < 4u) atomicOr(&ATrow[r_][sv_ >> 5], 1u << (sv_ & 31)); }
    for (int e4 = tid; e4 < (E >> 2); e4 += 256) {
        int4 s4 = s4p[e4], d4 = d4p[e4];
        EDGE_ROW(s4.x, d4.x)
        EDGE_ROW(s4.y, d4.y)
        EDGE_ROW(s4.z, d4.z)
        EDGE_ROW(s4.w, d4.w)
    }
    for (int e = (E & ~3) + tid; e < E; e += 256)   // tail (E%4)
        EDGE_ROW(ei[e], ei[E + e])
#undef EDGE_ROW
    __syncthreads();
    int w = tid >> 6, lane = tid & 63;
    Abits[(blk * 4 + w) * NW + lane]  = Arow[w][lane];
    ATbits[(blk * 4 + w) * NW + lane] = ATrow[w][lane];
}

// ---- K2: pandeg (round-0 structure, 1 node/block, 32 waves/CU) + fused lin1
__global__ void __launch_bounds__(256) k_pandeg_lin1(
        const unsigned* __restrict__ Abits,
        const float* __restrict__ fw1, const float* __restrict__ fw2,
        const float* __restrict__ x, const float* __restrict__ W1,
        const float* __restrict__ b1,
        float* __restrict__ dinv1, float* __restrict__ dinv2,
        float* __restrict__ y1) {
    __shared__ int cnt[NN];
    __shared__ unsigned rowbits[NW];
    __shared__ int neigh[NN];
    __shared__ int ncnt;
    __shared__ int red1[4], red2[4];
    __shared__ float xs[528];            // 512 + 16 group-pad
    __shared__ float sd1;

    int i = blockIdx.x, tid = threadIdx.x;
    for (int j = tid; j < NN; j += 256) cnt[j] = 0;
    if (tid < NW) rowbits[tid] = Abits[i * NW + tid];
    if (tid == 0) ncnt = 0;
    __syncthreads();

    if (tid < NW) {                      // enumerate out-neighbors of i
        unsigned bits = rowbits[tid];
        while (bits) {
            int b = __ffs(bits) - 1; bits &= bits - 1;
            int slot = atomicAdd(&ncnt, 1);
            if (slot < NN) neigh[slot] = tid * 32 + b;
        }
    }
    __syncthreads();

    int lane = tid & 63, grp = tid >> 6;
    int nc = ncnt < NN ? ncnt : NN;
    {
        int n = grp;                     // 1-deep prefetch of neighbor rows
        unsigned nxt = (n < nc) ? Abits[neigh[n] * NW + lane] : 0u;
        for (; n < nc; n += 4) {
            unsigned bits = nxt;
            if (n + 4 < nc) nxt = Abits[neigh[n + 4] * NW + lane];
            while (bits) {
                int b = __ffs(bits) - 1; bits &= bits - 1;
                atomicAdd(&cnt[lane * 32 + b], 1);
            }
        }
    }
    __syncthreads();

    float w10 = fw1[0], w11 = fw1[1], w12 = fw1[2];
    float w20 = fw2[0], w21 = fw2[1], w22 = fw2[2];
    int c1 = 0, c2 = 0;
    for (int j = tid; j < NN; j += 256) {
        float a = ((rowbits[j >> 5] >> (j & 31)) & 1u) ? 1.f : 0.f;
        float c = (float)cnt[j];
        float dg = (j == i) ? 1.f : 0.f;
        c1 += ((w10 * dg + w11 * a + w12 * c) != 0.f);
        c2 += ((w20 * dg + w21 * a + w22 * c) != 0.f);
    }
    for (int o = 32; o; o >>= 1) { c1 += __shfl_down(c1, o); c2 += __shfl_down(c2, o); }
    if (lane == 0) { red1[grp] = c1; red2[grp] = c2; }
    __syncthreads();
    if (tid == 0) {
        int d1 = red1[0] + red1[1] + red1[2] + red1[3];
        int d2 = red2[0] + red2[1] + red2[2] + red2[3];
        float v1 = d1 > 0 ? rsqrtf((float)d1) : 0.f;
        float v2 = d2 > 0 ? rsqrtf((float)d2) : 0.f;
        dinv1[i] = v1; dinv2[i] = v2; sd1 = v1;
    }
    // ---- fused lin1: y1[i][c] = dinv1[i]*(x[i,:].W1[c,:] + b1[c]) ----------
    if (tid < 128) {                     // coalesced float4 stage
        float4 v = ((const float4*)(x + i * 512))[tid];
        int f = tid * 4, m = f + (f >> 5);   // group-pad: conflict-free
        xs[m] = v.x; xs[m + 1] = v.y; xs[m + 2] = v.z; xs[m + 3] = v.w;
    }
    __syncthreads();
    int c = tid >> 4, seg = tid & 15;    // 16 channels x 16 segments
    const float* wr = W1 + c * 512 + seg * 32;
    const float* xr = xs + seg * 33;
    float s = 0.f;
#pragma unroll
    for (int f = 0; f < 32; f++) s += xr[f] * wr[f];
    for (int o = 8; o; o >>= 1) s += __shfl_down(s, o, 16);
    if (seg == 0) y1[i * 16 + c] = sd1 * (s + b1[c]);
}

// ---- K3: two-hop layer-1 tail + fused lin2 ---------------------------------
// t1_i = sum_{j in Nin(i)} y1[j];  u_i = sum_{j in Nin(i)} t1_j
// h = relu(dinv1*(w0*y1_i + w1*t1_i + w2*u_i));  y2 = dinv2*(W2 h + b2)
__global__ void __launch_bounds__(256) k_l1tail_lin2(
        const unsigned* __restrict__ ATbits, const float* __restrict__ y1,
        const float* __restrict__ dinv1, const float* __restrict__ dinv2,
        const float* __restrict__ fw, const float* __restrict__ W2,
        const float* __restrict__ b2, float* __restrict__ y2) {
    __shared__ int nin[64];
    __shared__ int nintot;
    __shared__ int njn[4][64];
    __shared__ float tacc[4][16], uacc[4][16];
    __shared__ float hvec[16];
    int i = blockIdx.x, tid = threadIdx.x, w = tid >> 6, lane = tid & 63;

    if (w == 0) {                        // deterministic prefix enumeration
        unsigned bits = ATbits[i * NW + lane];
        int pc = __popc(bits), incl = pc;
#pragma unroll
        for (int o = 1; o < 64; o <<= 1) { int v = __shfl_up(incl, o); if (lane >= o) incl += v; }
        int slot = incl - pc;
        if (lane == 63) nintot = incl;
        while (bits) {
            int b = __ffs(bits) - 1; bits &= bits - 1;
            if (slot < 64) nin[slot] = lane * 32 + b;
            slot++;
        }
    }
    __syncthreads();
    int ncin = nintot < 64 ? nintot : 64;
    int c = lane & 15, kg = lane >> 4;
    float up = 0.f, tp = 0.f;
    int n = w;
    unsigned rowbits = (n < ncin) ? ATbits[nin[n] * NW + lane] : 0u;
    for (; n < ncin; n += 4) {           // each wave owns j = nin[w], nin[w+4]..
        unsigned bits = rowbits;
        if (n + 4 < ncin) rowbits = ATbits[nin[n + 4] * NW + lane];
        int pc = __popc(bits), incl = pc;
#pragma unroll
        for (int o = 1; o < 64; o <<= 1) { int v = __shfl_up(incl, o); if (lane >= o) incl += v; }
        int slot = incl - pc;
        int cnt2 = __shfl(incl, 63);
        while (bits) {
            int b = __ffs(bits) - 1; bits &= bits - 1;
            if (slot < 64) njn[w][slot] = lane * 32 + b;   // wave-private
            slot++;
        }
        cnt2 = cnt2 < 64 ? cnt2 : 64;
        float tj = 0.f;                  // t1_j: 16 channels x 4-way k split
        for (int n2 = kg; n2 < cnt2; n2 += 4) tj += y1[njn[w][n2] * 16 + c];
        tj += __shfl_down(tj, 32);
        tj += __shfl_down(tj, 16);       // lanes 0..15 hold t1_j[c]
        if (kg == 0) { up += tj; tp += y1[nin[n] * 16 + c]; }
    }
    if (kg == 0) { uacc[w][c] = up; tacc[w][c] = tp; }
    __syncthreads();
    if (tid < 16) {
        float t1i = tacc[0][tid] + tacc[1][tid] + tacc[2][tid] + tacc[3][tid];
        float ui  = uacc[0][tid] + uacc[1][tid] + uacc[2][tid] + uacc[3][tid];
        float z = dinv1[i] * (fw[0] * y1[i * 16 + tid] + fw[1] * t1i + fw[2] * ui);
        hvec[tid] = z > 0.f ? z : 0.f;   // relu
    }
    __syncthreads();
    if (tid < 32) {                      // fused lin2
        float s2 = 0.f;
#pragma unroll
        for (int f = 0; f < 16; f++) s2 += hvec[f] * W2[tid * 16 + f];
        y2[i * 32 + tid] = dinv2[i] * (s2 + b2[tid]);
    }
}

// ---- K4: two-hop layer-2 tail + log_softmax --------------------------------
__global__ void __launch_bounds__(256) k_l2tail(
        const unsigned* __restrict__ ATbits, const float* __restrict__ y2,
        const float* __restrict__ dinv2, const float* __restrict__ fw,
        float* __restrict__ out) {
    __shared__ int nin[64];
    __shared__ int nintot;
    __shared__ int njn[4][64];
    __shared__ float tacc[4][32], uacc[4][32];
    int i = blockIdx.x, tid = threadIdx.x, w = tid >> 6, lane = tid & 63;

    if (w == 0) {
        unsigned bits = ATbits[i * NW + lane];
        int pc = __popc(bits), incl = pc;
#pragma unroll
        for (int o = 1; o < 64; o <<= 1) { int v = __shfl_up(incl, o); if (lane >= o) incl += v; }
        int slot = incl - pc;
        if (lane == 63) nintot = incl;
        while (bits) {
            int b = __ffs(bits) - 1; bits &= bits - 1;
            if (slot < 64) nin[slot] = lane * 32 + b;
            slot++;
        }
    }
    __syncthreads();
    int ncin = nintot < 64 ? nintot : 64;
    int c = lane & 31, kg = lane >> 5;
    float up = 0.f, tp = 0.f;
    int n = w;
    unsigned rowbits = (n < ncin) ? ATbits[nin[n] * NW + lane] : 0u;
    for (; n < ncin; n += 4) {
        unsigned bits = rowbits;
        if (n + 4 < ncin) rowbits = ATbits[nin[n + 4] * NW + lane];
        int pc = __popc(bits), incl = pc;
#pragma unroll
        for (int o = 1; o < 64; o <<= 1) { int v = __shfl_up(incl, o); if (lane >= o) incl += v; }
        int slot = incl - pc;
        int cnt2 = __shfl(incl, 63);
        while (bits) {
            int b = __ffs(bits) - 1; bits &= bits - 1;
            if (slot < 64) njn[w][slot] = lane * 32 + b;
            slot++;
        }
        cnt2 = cnt2 < 64 ? cnt2 : 64;
        float tj = 0.f;                  // t2_j: 32 channels x 2-way k split
        for (int n2 = kg; n2 < cnt2; n2 += 2) tj += y2[njn[w][n2] * 32 + c];
        tj += __shfl_down(tj, 32);       // lanes 0..31 hold t2_j[c]
        if (kg == 0) { up += tj; tp += y2[nin[n] * 32 + c]; }
    }
    if (kg == 0) { uacc[w][c] = up; tacc[w][c] = tp; }
    __syncthreads();
    if (tid < 32) {
        float t2i = tacc[0][tid] + tacc[1][tid] + tacc[2][tid] + tacc[3][tid];
        float ui  = uacc[0][tid] + uacc[1][tid] + uacc[2][tid] + uacc[3][tid];
        float o = dinv2[i] * (fw[0] * y2[i * 32 + tid] + fw[1] * t2i + fw[2] * ui);
        float m = o;                     // log_softmax over 32 channels
        for (int k = 16; k; k >>= 1) m = fmaxf(m, __shfl_xor(m, k, 32));
        float e = expf(o - m);
        float ssum = e;
        for (int k = 16; k; k >>= 1) ssum += __shfl_xor(ssum, k, 32);
        out[i * 32 + tid] = o - m - logf(ssum);
    }
}

extern "C" void kernel_launch(void* const* d_in, const int* in_sizes, int n_in,
                              void* d_out, int out_size, void* d_ws, size_t ws_size,
                              hipStream_t stream) {
    const float* x   = (const float*)d_in[0];
    const int*   ei  = (const int*)d_in[1];
    const float* fw1 = (const float*)d_in[2];
    const float* W1  = (const float*)d_in[3];
    const float* b1  = (const float*)d_in[4];
    const float* fw2 = (const float*)d_in[5];
    const float* W2  = (const float*)d_in[6];
    const float* b2  = (const float*)d_in[7];
    float* out = (float*)d_out;
    int E = in_sizes[1] / 2;

    char* ws = (char*)d_ws;
    size_t off = 0;
    auto alloc = [&](size_t bytes) { void* p = ws + off; off += (bytes + 255) & ~size_t(255); return p; };
    unsigned* Abits  = (unsigned*)alloc(NN * NW * 4);
    unsigned* ATbits = (unsigned*)alloc(NN * NW * 4);
    float* dinv1 = (float*)alloc(NN * 4);
    float* dinv2 = (float*)alloc(NN * 4);
    float* y1 = (float*)alloc(NN * 16 * 4);
    float* y2 = (float*)alloc(NN * 32 * 4);
    (void)ws_size; (void)n_in; (void)out_size;

    k_build<<<BBLK, 256, 0, stream>>>(ei, E, Abits, ATbits);
    k_pandeg_lin1<<<NN, 256, 0, stream>>>(Abits, fw1, fw2, x, W1, b1, dinv1, dinv2, y1);
    k_l1tail_lin2<<<NN, 256, 0, stream>>>(ATbits, y1, dinv1, dinv2, fw1, W2, b2, y2);
    k_l2tail<<<NN, 256, 0, stream>>>(ATbits, y2, dinv2, fw2, out);
}

// Round 3
// 122.551 us; speedup vs baseline: 3.1421x; 1.0995x over previous
//
#include <hip/hip_runtime.h>

#define NN 2048   // nodes
#define NW 64     // u32 words per bitmap row (2048 bits)
#define RB 16     // rows per build block

// ---- K1: block-local adjacency build, 16 rows/block ------------------------
// Each block scans the edge list (256 KB, L2-resident) and keeps edges
// touching its 16 rows; writes deduped A and A^T row bitmaps. No zero pass,
// no global atomics. 128 blocks -> 32 MB aggregate L2 scan traffic.
__global__ void __launch_bounds__(256) k_build(const int* __restrict__ ei, int E,
        unsigned* __restrict__ Abits, unsigned* __restrict__ ATbits) {
    __shared__ unsigned Arow[RB][NW], ATrow[RB][NW];
    int tid = threadIdx.x, blk = blockIdx.x;
    for (int t = tid; t < RB * NW; t += 256) {
        (&Arow[0][0])[t] = 0u; (&ATrow[0][0])[t] = 0u;
    }
    __syncthreads();
    const int4* s4p = (const int4*)ei;
    const int4* d4p = (const int4*)(ei + E);
    const int base = blk * RB;
#define EDGE_ROW(SS, DD) { \
        int sv_ = (SS) & (NN - 1), dv_ = (DD) & (NN - 1); \
        int r_ = sv_ - base; \
        if ((unsigned)r_ < (unsigned)RB) atomicOr(&Arow[r_][dv_ >> 5], 1u << (dv_ & 31)); \
        r_ = dv_ - base; \
        if ((unsigned)r_ < (unsigned)RB) atomicOr(&ATrow[r_][sv_ >> 5], 1u << (sv_ & 31)); }
    for (int e4 = tid; e4 < (E >> 2); e4 += 256) {
        int4 s4 = s4p[e4], d4 = d4p[e4];
        EDGE_ROW(s4.x, d4.x)
        EDGE_ROW(s4.y, d4.y)
        EDGE_ROW(s4.z, d4.z)
        EDGE_ROW(s4.w, d4.w)
    }
    for (int e = (E & ~3) + tid; e < E; e += 256)   // tail (E%4)
        EDGE_ROW(ei[e], ei[E + e])
#undef EDGE_ROW
    __syncthreads();
    int w = tid >> 6, lane = tid & 63;
    for (int r = w; r < RB; r += 4) {               // coalesced 256B row stores
        Abits[(blk * RB + r) * NW + lane]  = Arow[r][lane];
        ATbits[(blk * RB + r) * NW + lane] = ATrow[r][lane];
    }
}

// ---- K2: pandeg (round-0 structure, 1 node/block) + fused lin1 -------------
__global__ void __launch_bounds__(256) k_pandeg_lin1(
        const unsigned* __restrict__ Abits,
        const float* __restrict__ fw1, const float* __restrict__ fw2,
        const float* __restrict__ x, const float* __restrict__ W1,
        const float* __restrict__ b1,
        float* __restrict__ dinv1, float* __restrict__ dinv2,
        float* __restrict__ y1) {
    __shared__ int cnt[NN];
    __shared__ unsigned rowbits[NW];
    __shared__ int neigh[NN];
    __shared__ int ncnt;
    __shared__ int red1[4], red2[4];
    __shared__ float xs[528];            // 512 + 16 group-pad
    __shared__ float sd1;

    int i = blockIdx.x, tid = threadIdx.x;
    for (int j = tid; j < NN; j += 256) cnt[j] = 0;
    if (tid < NW) rowbits[tid] = Abits[i * NW + tid];
    if (tid == 0) ncnt = 0;
    __syncthreads();

    if (tid < NW) {                      // enumerate out-neighbors of i
        unsigned bits = rowbits[tid];
        while (bits) {
            int b = __ffs(bits) - 1; bits &= bits - 1;
            int slot = atomicAdd(&ncnt, 1);
            if (slot < NN) neigh[slot] = tid * 32 + b;
        }
    }
    __syncthreads();

    int lane = tid & 63, grp = tid >> 6;
    int nc = ncnt < NN ? ncnt : NN;
    {
        int n = grp;                     // 1-deep prefetch of neighbor rows
        unsigned nxt = (n < nc) ? Abits[neigh[n] * NW + lane] : 0u;
        for (; n < nc; n += 4) {
            unsigned bits = nxt;
            if (n + 4 < nc) nxt = Abits[neigh[n + 4] * NW + lane];
            while (bits) {
                int b = __ffs(bits) - 1; bits &= bits - 1;
                atomicAdd(&cnt[lane * 32 + b], 1);
            }
        }
    }
    __syncthreads();

    float w10 = fw1[0], w11 = fw1[1], w12 = fw1[2];
    float w20 = fw2[0], w21 = fw2[1], w22 = fw2[2];
    int c1 = 0, c2 = 0;
    for (int j = tid; j < NN; j += 256) {
        float a = ((rowbits[j >> 5] >> (j & 31)) & 1u) ? 1.f : 0.f;
        float c = (float)cnt[j];
        float dg = (j == i) ? 1.f : 0.f;
        c1 += ((w10 * dg + w11 * a + w12 * c) != 0.f);
        c2 += ((w20 * dg + w21 * a + w22 * c) != 0.f);
    }
    for (int o = 32; o; o >>= 1) { c1 += __shfl_down(c1, o); c2 += __shfl_down(c2, o); }
    if (lane == 0) { red1[grp] = c1; red2[grp] = c2; }
    __syncthreads();
    if (tid == 0) {
        int d1 = red1[0] + red1[1] + red1[2] + red1[3];
        int d2 = red2[0] + red2[1] + red2[2] + red2[3];
        float v1 = d1 > 0 ? rsqrtf((float)d1) : 0.f;
        float v2 = d2 > 0 ? rsqrtf((float)d2) : 0.f;
        dinv1[i] = v1; dinv2[i] = v2; sd1 = v1;
    }
    // ---- fused lin1: y1[i][c] = dinv1[i]*(x[i,:].W1[c,:] + b1[c]) ----------
    if (tid < 128) {                     // coalesced float4 stage
        float4 v = ((const float4*)(x + i * 512))[tid];
        int f = tid * 4, m = f + (f >> 5);   // group-pad: conflict-free
        xs[m] = v.x; xs[m + 1] = v.y; xs[m + 2] = v.z; xs[m + 3] = v.w;
    }
    __syncthreads();
    int c = tid >> 4, seg = tid & 15;    // 16 channels x 16 segments
    const float* wr = W1 + c * 512 + seg * 32;
    const float* xr = xs + seg * 33;
    float s = 0.f;
#pragma unroll
    for (int f = 0; f < 32; f++) s += xr[f] * wr[f];
    for (int o = 8; o; o >>= 1) s += __shfl_down(s, o, 16);
    if (seg == 0) y1[i * 16 + c] = sd1 * (s + b1[c]);
}

// ---- K3: SpMM F=16: t[i][:] = sum_{j: A[j][i]=1} y1[j][:] ------------------
// 4 rows per block (one wave per row). Round-0 proven.
__global__ void __launch_bounds__(256) k_spmm16(
        const unsigned* __restrict__ ATbits, const float* __restrict__ y,
        float* __restrict__ t) {
    __shared__ int neigh[4][64];
    __shared__ int ncnt[4];
    int tid = threadIdx.x, w = tid >> 6, lane = tid & 63;
    int i = blockIdx.x * 4 + w;
    if (lane == 0) ncnt[w] = 0;
    __syncthreads();
    unsigned bits = ATbits[i * NW + lane];
    while (bits) {
        int b = __ffs(bits) - 1; bits &= bits - 1;
        int slot = atomicAdd(&ncnt[w], 1);
        if (slot < 64) neigh[w][slot] = lane * 32 + b;
    }
    __syncthreads();
    int nc = ncnt[w] < 64 ? ncnt[w] : 64;
    int c = lane & 15, grp = lane >> 4;
    float acc = 0.f;
    for (int n = grp; n < nc; n += 4) acc += y[neigh[w][n] * 16 + c];
    acc += __shfl_down(acc, 32);
    acc += __shfl_down(acc, 16);
    if (lane < 16) t[i * 16 + c] = acc;
}

// ---- K4: layer-1 tail + FUSED layer-2 linear -------------------------------
// h = relu(dinv1*(w0*y1 + w1*t1 + w2*(P t1)));  y2[i][c2] = dinv2*(h.W2[c2]+b2)
__global__ void __launch_bounds__(256) k_final1_lin2(
        const unsigned* __restrict__ ATbits, const float* __restrict__ y,
        const float* __restrict__ t, const float* __restrict__ dinv1,
        const float* __restrict__ dinv2, const float* __restrict__ fw,
        const float* __restrict__ W2, const float* __restrict__ b2,
        float* __restrict__ y2) {
    __shared__ int neigh[4][64];
    __shared__ int ncnt[4];
    int tid = threadIdx.x, w = tid >> 6, lane = tid & 63;
    int i = blockIdx.x * 4 + w;
    if (lane == 0) ncnt[w] = 0;
    __syncthreads();
    unsigned bits = ATbits[i * NW + lane];
    while (bits) {
        int b = __ffs(bits) - 1; bits &= bits - 1;
        int slot = atomicAdd(&ncnt[w], 1);
        if (slot < 64) neigh[w][slot] = lane * 32 + b;
    }
    __syncthreads();
    int nc = ncnt[w] < 64 ? ncnt[w] : 64;
    int c = lane & 15, grp = lane >> 4;
    float acc = 0.f;
    for (int n = grp; n < nc; n += 4) acc += t[neigh[w][n] * 16 + c];
    acc += __shfl_down(acc, 32);
    acc += __shfl_down(acc, 16);
    // h value (valid on lanes 0..15; computed on all lanes, garbage elsewhere)
    float z = fw[0] * y[i * 16 + c] + fw[1] * t[i * 16 + c] + fw[2] * acc;
    z *= dinv1[i];
    z = z > 0.f ? z : 0.f;
    // fused layer-2 linear: lanes 0..31 each produce one output channel
    float s2 = 0.f;
#pragma unroll
    for (int f = 0; f < 16; f++) s2 += __shfl(z, f) * W2[lane * 16 + f];
    if (lane < 32) y2[i * 32 + lane] = dinv2[i] * (s2 + b2[lane]);
}

// ---- K5: SpMM F=32: t2 = P y2 ----------------------------------------------
__global__ void __launch_bounds__(256) k_spmm32(
        const unsigned* __restrict__ ATbits, const float* __restrict__ y,
        float* __restrict__ t) {
    __shared__ int neigh[4][64];
    __shared__ int ncnt[4];
    int tid = threadIdx.x, w = tid >> 6, lane = tid & 63;
    int i = blockIdx.x * 4 + w;
    if (lane == 0) ncnt[w] = 0;
    __syncthreads();
    unsigned bits = ATbits[i * NW + lane];
    while (bits) {
        int b = __ffs(bits) - 1; bits &= bits - 1;
        int slot = atomicAdd(&ncnt[w], 1);
        if (slot < 64) neigh[w][slot] = lane * 32 + b;
    }
    __syncthreads();
    int nc = ncnt[w] < 64 ? ncnt[w] : 64;
    int c = lane & 31, grp = lane >> 5;
    float acc = 0.f;
    for (int n = grp; n < nc; n += 2) acc += y[neigh[w][n] * 32 + c];
    acc += __shfl_down(acc, 32);
    if (lane < 32) t[i * 32 + c] = acc;
}

// ---- K6: layer-2 tail + log_softmax -> fp32 --------------------------------
__global__ void __launch_bounds__(256) k_final2(
        const unsigned* __restrict__ ATbits, const float* __restrict__ y,
        const float* __restrict__ t, const float* __restrict__ dinv,
        const float* __restrict__ fw, float* __restrict__ out) {
    __shared__ int neigh[4][64];
    __shared__ int ncnt[4];
    int tid = threadIdx.x, w = tid >> 6, lane = tid & 63;
    int i = blockIdx.x * 4 + w;
    if (lane == 0) ncnt[w] = 0;
    __syncthreads();
    unsigned bits = ATbits[i * NW + lane];
    while (bits) {
        int b = __ffs(bits) - 1; bits &= bits - 1;
        int slot = atomicAdd(&ncnt[w], 1);
        if (slot < 64) neigh[w][slot] = lane * 32 + b;
    }
    __syncthreads();
    int nc = ncnt[w] < 64 ? ncnt[w] : 64;
    int c = lane & 31, grp = lane >> 5;
    float acc = 0.f;
    for (int n = grp; n < nc; n += 2) acc += t[neigh[w][n] * 32 + c];
    acc += __shfl_down(acc, 32);               // lanes 0..31 hold full sum
    float o = dinv[i] * (fw[0] * y[i * 32 + c] + fw[1] * t[i * 32 + c] + fw[2] * acc);
    // log_softmax across lanes 0..31 (width-32 partitions keep hi lanes out)
    float m = o;
    for (int k = 16; k; k >>= 1) m = fmaxf(m, __shfl_xor(m, k, 32));
    float e = expf(o - m);
    float ssum = e;
    for (int k = 16; k; k >>= 1) ssum += __shfl_xor(ssum, k, 32);
    if (lane < 32) out[i * 32 + c] = o - m - logf(ssum);
}

extern "C" void kernel_launch(void* const* d_in, const int* in_sizes, int n_in,
                              void* d_out, int out_size, void* d_ws, size_t ws_size,
                              hipStream_t stream) {
    const float* x   = (const float*)d_in[0];
    const int*   ei  = (const int*)d_in[1];
    const float* fw1 = (const float*)d_in[2];
    const float* W1  = (const float*)d_in[3];
    const float* b1  = (const float*)d_in[4];
    const float* fw2 = (const float*)d_in[5];
    const float* W2  = (const float*)d_in[6];
    const float* b2  = (const float*)d_in[7];
    float* out = (float*)d_out;
    int E = in_sizes[1] / 2;

    char* ws = (char*)d_ws;
    size_t off = 0;
    auto alloc = [&](size_t bytes) { void* p = ws + off; off += (bytes + 255) & ~size_t(255); return p; };
    unsigned* Abits  = (unsigned*)alloc(NN * NW * 4);
    unsigned* ATbits = (unsigned*)alloc(NN * NW * 4);
    float* dinv1 = (float*)alloc(NN * 4);
    float* dinv2 = (float*)alloc(NN * 4);
    float* y1 = (float*)alloc(NN * 16 * 4);
    float* t1 = (float*)alloc(NN * 16 * 4);
    float* y2 = (float*)alloc(NN * 32 * 4);
    float* t2 = (float*)alloc(NN * 32 * 4);
    (void)ws_size; (void)n_in; (void)out_size;

    k_build<<<NN / RB, 256, 0, stream>>>(ei, E, Abits, ATbits);
    k_pandeg_lin1<<<NN, 256, 0, stream>>>(Abits, fw1, fw2, x, W1, b1, dinv1, dinv2, y1);
    k_spmm16<<<NN / 4, 256, 0, stream>>>(ATbits, y1, t1);
    k_final1_lin2<<<NN / 4, 256, 0, stream>>>(ATbits, y1, t1, dinv1, dinv2, fw1, W2, b2, y2);
    k_spmm32<<<NN / 4, 256, 0, stream>>>(ATbits, y2, t2);
    k_final2<<<NN / 4, 256, 0, stream>>>(ATbits, y2, t2, dinv2, fw2, out);
}

// Round 4
// 110.727 us; speedup vs baseline: 3.4776x; 1.1068x over previous
//
#include <hip/hip_runtime.h>

#define NN 2048   // nodes
#define NW 64     // u32 words per bitmap row (2048 bits)

// ---------------- build A and A^T as row bitmaps (dedups duplicate edges) ---
// (round-0 exact; bitmaps pre-zeroed by hipMemsetAsync)
__global__ void k_build(const int* __restrict__ ei, int E,
                        unsigned* __restrict__ Abits, unsigned* __restrict__ ATbits) {
    int e = blockIdx.x * blockDim.x + threadIdx.x;
    if (e >= E) return;
    int s = ei[e] & (NN - 1);        // edge_index[0] = source
    int d = ei[E + e] & (NN - 1);    // edge_index[1] = target
    atomicOr(&Abits[s * NW + (d >> 5)], 1u << (d & 31));
    atomicOr(&ATbits[d * NW + (s >> 5)], 1u << (s & 31));
}

// ---------------- pandeg (round-0 exact) + fused lin1 tail ------------------
// pan[i][j] = w0*(i==j) + w1*A[i][j] + w2*paths2(i,j); exact integer counts.
// Tail: y1[i][c] = dinv1[i]*(x[i,:].W1[c,:] + b1[c])
__global__ void __launch_bounds__(256) k_pandeg_lin1(
        const unsigned* __restrict__ Abits,
        const float* __restrict__ fw1, const float* __restrict__ fw2,
        const float* __restrict__ x, const float* __restrict__ W1,
        const float* __restrict__ b1,
        float* __restrict__ dinv1, float* __restrict__ dinv2,
        float* __restrict__ y1) {
    __shared__ int cnt[NN];
    __shared__ unsigned rowbits[NW];
    __shared__ int neigh[NN];
    __shared__ int ncnt;
    __shared__ int red1[4], red2[4];
    __shared__ float xs[528];            // 512 + 16 group-pad
    __shared__ float sd1;

    int i = blockIdx.x, tid = threadIdx.x;
    for (int j = tid; j < NN; j += 256) cnt[j] = 0;
    if (tid < NW) rowbits[tid] = Abits[i * NW + tid];
    if (tid == 0) ncnt = 0;
    __syncthreads();

    if (tid < NW) {                       // enumerate out-neighbors of i
        unsigned bits = rowbits[tid];
        while (bits) {
            int b = __ffs(bits) - 1; bits &= bits - 1;
            int slot = atomicAdd(&ncnt, 1);
            if (slot < NN) neigh[slot] = tid * 32 + b;
        }
    }
    __syncthreads();

    int lane = tid & 63, grp = tid >> 6;
    int nc = ncnt < NN ? ncnt : NN;
    for (int n = grp; n < nc; n += 4) {   // scatter: +1 at every j in N(k)
        int k = neigh[n];
        unsigned bits = Abits[k * NW + lane];
        while (bits) {
            int b = __ffs(bits) - 1; bits &= bits - 1;
            atomicAdd(&cnt[lane * 32 + b], 1);
        }
    }
    __syncthreads();

    float w10 = fw1[0], w11 = fw1[1], w12 = fw1[2];
    float w20 = fw2[0], w21 = fw2[1], w22 = fw2[2];
    int c1 = 0, c2 = 0;
    for (int j = tid; j < NN; j += 256) {
        float a = ((rowbits[j >> 5] >> (j & 31)) & 1u) ? 1.f : 0.f;
        float c = (float)cnt[j];
        float dg = (j == i) ? 1.f : 0.f;
        c1 += ((w10 * dg + w11 * a + w12 * c) != 0.f);
        c2 += ((w20 * dg + w21 * a + w22 * c) != 0.f);
    }
    for (int o = 32; o; o >>= 1) { c1 += __shfl_down(c1, o); c2 += __shfl_down(c2, o); }
    if (lane == 0) { red1[grp] = c1; red2[grp] = c2; }
    __syncthreads();
    if (tid == 0) {
        int d1 = red1[0] + red1[1] + red1[2] + red1[3];
        int d2 = red2[0] + red2[1] + red2[2] + red2[3];
        float v1 = d1 > 0 ? rsqrtf((float)d1) : 0.f;
        float v2 = d2 > 0 ? rsqrtf((float)d2) : 0.f;
        dinv1[i] = v1; dinv2[i] = v2; sd1 = v1;
    }
    // ---- fused lin1 (round-0 k_lin1 body, dinv read from LDS) --------------
    if (tid < 128) {                      // coalesced float4 stage
        float4 v = ((const float4*)(x + i * 512))[tid];
        int f = tid * 4;
        int m = f + (f >> 5);             // group-pad: conflict-free
        xs[m] = v.x; xs[m + 1] = v.y; xs[m + 2] = v.z; xs[m + 3] = v.w;
    }
    __syncthreads();
    int c = tid >> 4, seg = tid & 15;     // 16 channels x 16 segments
    const float* wr = W1 + c * 512 + seg * 32;
    const float* xr = xs + seg * 33;
    float s = 0.f;
#pragma unroll
    for (int f = 0; f < 32; f++) s += xr[f] * wr[f];
    for (int o = 8; o; o >>= 1) s += __shfl_down(s, o, 16);
    if (seg == 0) y1[i * 16 + c] = sd1 * (s + b1[c]);
}

// ---------------- SpMM F=16: t[i][:] = sum_{j: A[j][i]=1} y1[j][:] ----------
// (round-0 exact) 4 rows per block, one wave per row.
__global__ void __launch_bounds__(256) k_spmm16(
        const unsigned* __restrict__ ATbits, const float* __restrict__ y,
        float* __restrict__ t) {
    __shared__ int neigh[4][64];
    __shared__ int ncnt[4];
    int tid = threadIdx.x, w = tid >> 6, lane = tid & 63;
    int i = blockIdx.x * 4 + w;
    if (lane == 0) ncnt[w] = 0;
    __syncthreads();
    unsigned bits = ATbits[i * NW + lane];
    while (bits) {
        int b = __ffs(bits) - 1; bits &= bits - 1;
        int slot = atomicAdd(&ncnt[w], 1);
        if (slot < 64) neigh[w][slot] = lane * 32 + b;
    }
    __syncthreads();
    int nc = ncnt[w] < 64 ? ncnt[w] : 64;
    int c = lane & 15, grp = lane >> 4;
    float acc = 0.f;
    for (int n = grp; n < nc; n += 4) acc += y[neigh[w][n] * 16 + c];
    acc += __shfl_down(acc, 32);
    acc += __shfl_down(acc, 16);
    if (lane < 16) t[i * 16 + c] = acc;
}

// ---- layer-1 tail + FUSED layer-2 linear (round-0 exact) -------------------
// h = relu(dinv1*(w0*y1 + w1*t1 + w2*(P t1)));  y2[i][c2] = dinv2*(h.W2[c2]+b2)
__global__ void __launch_bounds__(256) k_final1_lin2(
        const unsigned* __restrict__ ATbits, const float* __restrict__ y,
        const float* __restrict__ t, const float* __restrict__ dinv1,
        const float* __restrict__ dinv2, const float* __restrict__ fw,
        const float* __restrict__ W2, const float* __restrict__ b2,
        float* __restrict__ y2) {
    __shared__ int neigh[4][64];
    __shared__ int ncnt[4];
    int tid = threadIdx.x, w = tid >> 6, lane = tid & 63;
    int i = blockIdx.x * 4 + w;
    if (lane == 0) ncnt[w] = 0;
    __syncthreads();
    unsigned bits = ATbits[i * NW + lane];
    while (bits) {
        int b = __ffs(bits) - 1; bits &= bits - 1;
        int slot = atomicAdd(&ncnt[w], 1);
        if (slot < 64) neigh[w][slot] = lane * 32 + b;
    }
    __syncthreads();
    int nc = ncnt[w] < 64 ? ncnt[w] : 64;
    int c = lane & 15, grp = lane >> 4;
    float acc = 0.f;
    for (int n = grp; n < nc; n += 4) acc += t[neigh[w][n] * 16 + c];
    acc += __shfl_down(acc, 32);
    acc += __shfl_down(acc, 16);
    // h value (valid on lanes 0..15; computed on all lanes, garbage elsewhere)
    float z = fw[0] * y[i * 16 + c] + fw[1] * t[i * 16 + c] + fw[2] * acc;
    z *= dinv1[i];
    z = z > 0.f ? z : 0.f;
    // fused layer-2 linear: lanes 0..31 each produce one output channel
    float s2 = 0.f;
#pragma unroll
    for (int f = 0; f < 16; f++) s2 += __shfl(z, f) * W2[lane * 16 + f];
    if (lane < 32) y2[i * 32 + lane] = dinv2[i] * (s2 + b2[lane]);
}

// ---------------- SpMM F=32: t2 = P y2 (round-0 exact) ----------------------
__global__ void __launch_bounds__(256) k_spmm32(
        const unsigned* __restrict__ ATbits, const float* __restrict__ y,
        float* __restrict__ t) {
    __shared__ int neigh[4][64];
    __shared__ int ncnt[4];
    int tid = threadIdx.x, w = tid >> 6, lane = tid & 63;
    int i = blockIdx.x * 4 + w;
    if (lane == 0) ncnt[w] = 0;
    __syncthreads();
    unsigned bits = ATbits[i * NW + lane];
    while (bits) {
        int b = __ffs(bits) - 1; bits &= bits - 1;
        int slot = atomicAdd(&ncnt[w], 1);
        if (slot < 64) neigh[w][slot] = lane * 32 + b;
    }
    __syncthreads();
    int nc = ncnt[w] < 64 ? ncnt[w] : 64;
    int c = lane & 31, grp = lane >> 5;
    float acc = 0.f;
    for (int n = grp; n < nc; n += 2) acc += y[neigh[w][n] * 32 + c];
    acc += __shfl_down(acc, 32);
    if (lane < 32) t[i * 32 + c] = acc;
}

// ---------------- layer-2 tail + log_softmax -> fp32 (round-0 exact) --------
__global__ void __launch_bounds__(256) k_final2(
        const unsigned* __restrict__ ATbits, const float* __restrict__ y,
        const float* __restrict__ t, const float* __restrict__ dinv,
        const float* __restrict__ fw, float* __restrict__ out) {
    __shared__ int neigh[4][64];
    __shared__ int ncnt[4];
    int tid = threadIdx.x, w = tid >> 6, lane = tid & 63;
    int i = blockIdx.x * 4 + w;
    if (lane == 0) ncnt[w] = 0;
    __syncthreads();
    unsigned bits = ATbits[i * NW + lane];
    while (bits) {
        int b = __ffs(bits) - 1; bits &= bits - 1;
        int slot = atomicAdd(&ncnt[w], 1);
        if (slot < 64) neigh[w][slot] = lane * 32 + b;
    }
    __syncthreads();
    int nc = ncnt[w] < 64 ? ncnt[w] : 64;
    int c = lane & 31, grp = lane >> 5;
    float acc = 0.f;
    for (int n = grp; n < nc; n += 2) acc += t[neigh[w][n] * 32 + c];
    acc += __shfl_down(acc, 32);               // lanes 0..31 hold full sum
    float o = dinv[i] * (fw[0] * y[i * 32 + c] + fw[1] * t[i * 32 + c] + fw[2] * acc);
    // log_softmax across lanes 0..31 (width-32 partitions keep hi lanes out)
    float m = o;
    for (int k = 16; k; k >>= 1) m = fmaxf(m, __shfl_xor(m, k, 32));
    float e = expf(o - m);
    float ssum = e;
    for (int k = 16; k; k >>= 1) ssum += __shfl_xor(ssum, k, 32);
    if (lane < 32) out[i * 32 + c] = o - m - logf(ssum);
}

extern "C" void kernel_launch(void* const* d_in, const int* in_sizes, int n_in,
                              void* d_out, int out_size, void* d_ws, size_t ws_size,
                              hipStream_t stream) {
    const float* x   = (const float*)d_in[0];
    const int*   ei  = (const int*)d_in[1];
    const float* fw1 = (const float*)d_in[2];
    const float* W1  = (const float*)d_in[3];
    const float* b1  = (const float*)d_in[4];
    const float* fw2 = (const float*)d_in[5];
    const float* W2  = (const float*)d_in[6];
    const float* b2  = (const float*)d_in[7];
    float* out = (float*)d_out;
    int E = in_sizes[1] / 2;

    char* ws = (char*)d_ws;
    size_t off = 0;
    auto alloc = [&](size_t bytes) { void* p = ws + off; off += (bytes + 255) & ~size_t(255); return p; };
    unsigned* Abits  = (unsigned*)alloc(NN * NW * 4);
    unsigned* ATbits = (unsigned*)alloc(NN * NW * 4);   // contiguous after Abits
    float* dinv1 = (float*)alloc(NN * 4);
    float* dinv2 = (float*)alloc(NN * 4);
    float* y1 = (float*)alloc(NN * 16 * 4);
    float* t1 = (float*)alloc(NN * 16 * 4);
    float* y2 = (float*)alloc(NN * 32 * 4);
    float* t2 = (float*)alloc(NN * 32 * 4);
    (void)ws_size; (void)n_in; (void)out_size;

    // zero both bitmap buffers (contiguous 1 MB) via a stream-ordered memset
    hipMemsetAsync(Abits, 0, (size_t)2 * NN * NW * 4, stream);
    k_build<<<(E + 255) / 256, 256, 0, stream>>>(ei, E, Abits, ATbits);
    k_pandeg_lin1<<<NN, 256, 0, stream>>>(Abits, fw1, fw2, x, W1, b1, dinv1, dinv2, y1);
    k_spmm16<<<NN / 4, 256, 0, stream>>>(ATbits, y1, t1);
    k_final1_lin2<<<NN / 4, 256, 0, stream>>>(ATbits, y1, t1, dinv1, dinv2, fw1, W2, b2, y2);
    k_spmm32<<<NN / 4, 256, 0, stream>>>(ATbits, y2, t2);
    k_final2<<<NN / 4, 256, 0, stream>>>(ATbits, y2, t2, dinv2, fw2, out);
}